// Round 11
// baseline (48.838 us; speedup 1.0000x reference)
//
#include <hip/hip_runtime.h>

#define L1V 1444
#define CRV 32
#define CHV 64
#define HWV 1600
#define KQ 448           // key slots per quarter (4*448 = 1792 >= 1780 used)
#define NTIL 28          // 16-key tiles per quarter
#define ROWH 20          // f16 per LDS row (40 B -> conflict-free reads)
#define NQT 91           // real query tiles (1456/16)

typedef float    f32x4 __attribute__((ext_vector_type(4)));
typedef _Float16 f16x4 __attribute__((ext_vector_type(4)));

// ---------------- K1: base = prelu(w1·x), wf = prelu(w2·avgpool(x)), global sumsq ----------------
__global__ __launch_bounds__(256) void k_front(const float* __restrict__ x,
    const float* __restrict__ w1, const float* __restrict__ b1, const float* __restrict__ a1,
    const float* __restrict__ w2, const float* __restrict__ b2, const float* __restrict__ a2,
    float* __restrict__ base, float* __restrict__ wf, float* __restrict__ sumsq)
{
    int t = blockIdx.x * 256 + threadIdx.x;
    float sq = 0.f;
    if (t < CRV * HWV) {                      // blocks 0..199: base
        int c = t / HWV, px = t - c * HWV;
        float acc = b1[c];
        #pragma unroll 8
        for (int ic = 0; ic < CHV; ++ic) acc += w1[c * CHV + ic] * x[ic * HWV + px];
        float a = a1[0];
        float v = acc >= 0.f ? acc : a * acc;
        base[t] = v;
        sq = v * v;
    } else {                                   // blocks 200..249: wf
        int u = t - CRV * HWV;                 // < 12800
        int c = u / 400, p = u - c * 400;
        int i = p / 20, j = p - i * 20;
        int px0 = (2 * i) * 40 + 2 * j;
        float acc = b2[c];
        for (int ic = 0; ic < CHV; ++ic) {
            const float* xp = x + ic * HWV + px0;
            float xd = 0.25f * (xp[0] + xp[1] + xp[40] + xp[41]);
            acc += w2[c * CHV + ic] * xd;
        }
        float a = a2[0];
        float v = acc >= 0.f ? acc : a * acc;
        wf[u] = v;
        sq = v * v;
    }
    __shared__ float red[256];
    red[threadIdx.x] = sq;
    __syncthreads();
    for (int s = 128; s > 0; s >>= 1) {
        if (threadIdx.x < s) red[threadIdx.x] += red[threadIdx.x + s];
        __syncthreads();
    }
    if (threadIdx.x == 0) atomicAdd(&sumsq[blockIdx.x < 200 ? 0 : 1], red[0]);
}

// ---------------- K2: MFMA flash-style patch attention (R9 body, key-quartered) ----------------
// grid = (12 qtile-groups, 32 ch, 4 key-quarters) = 1536 blocks = 6/CU
// -> 24 waves/CU = 6 waves/SIMD (R9 was grid-limited to 3/CU). block = 256
// (4 waves), 2 q-tiles/wave. Keys in LDS [448][20] f16 rows (ROWH=20:
// af b64 read at 40B stride is bank-conflict-free; b2 u16 gathers too):
// cols 0..8 pan, 9 = ones (0 on pads -> free den, pads contribute 0),
// 10..15 = 0 (read by b2), 16..19 pad (never read).
// Per 16-key tile: S^T = mfma(A=keys, B=queries) leaves P[q][l] in-lane for
// the PV A-fragment (R9-proven). Two accumulators (base/wf), tile-aligned.
__global__ __launch_bounds__(256) void k_attn(const float* __restrict__ base,
    const float* __restrict__ wf, const float* __restrict__ sumsq,
    float* __restrict__ part)
{
    __shared__ _Float16 panL[KQ * ROWH];      // 17,920 B
    const int qg   = blockIdx.x;              // 0..11
    const int c    = blockIdx.y;
    const int qtr  = blockIdx.z;              // key quarter 0..3
    const int tid  = threadIdx.x;
    const float bmax = sqrtf(sumsq[0]);
    const float wmax = sqrtf(sumsq[1]);
    const float invb = 1.0f / bmax, invw = 1.0f / wmax;
    const float SC = 14.4269504089f;          // SCALE * log2(e)

    // ---- stage this quarter's key slots ----
    for (int s = tid; s < KQ; s += 256) {
        int g = qtr * KQ + s;
        float v[9];
        float one = 0.f;
        if (g < L1V) {
            int i = g / 38, j = g - i * 38;
            const float* src = base + c * HWV + i * 40 + j;
            #pragma unroll
            for (int kh = 0; kh < 3; ++kh)
                #pragma unroll
                for (int kw = 0; kw < 3; ++kw) v[kh * 3 + kw] = src[kh * 40 + kw] * invb;
            one = 1.f;
        } else if (g >= 1456 && g < 1780) {
            int l2 = g - 1456;
            int i = l2 / 18, j = l2 - i * 18;
            const float* src = wf + c * 400 + i * 20 + j;
            #pragma unroll
            for (int kh = 0; kh < 3; ++kh)
                #pragma unroll
                for (int kw = 0; kw < 3; ++kw) v[kh * 3 + kw] = src[kh * 20 + kw] * invw;
            one = 1.f;
        } else {
            #pragma unroll
            for (int k = 0; k < 9; ++k) v[k] = 0.f;
        }
        f16x4 r0, r1, r2a, r3;
        r0[0] = (_Float16)v[0]; r0[1] = (_Float16)v[1]; r0[2] = (_Float16)v[2]; r0[3] = (_Float16)v[3];
        r1[0] = (_Float16)v[4]; r1[1] = (_Float16)v[5]; r1[2] = (_Float16)v[6]; r1[3] = (_Float16)v[7];
        r2a[0] = (_Float16)v[8]; r2a[1] = (_Float16)one; r2a[2] = (_Float16)0.f; r2a[3] = (_Float16)0.f;
        r3 = (f16x4)(_Float16)0.f;
        _Float16* row = &panL[s * ROWH];
        *(f16x4*)&row[0]  = r0;
        *(f16x4*)&row[4]  = r1;
        *(f16x4*)&row[8]  = r2a;
        *(f16x4*)&row[12] = r3;               // cols 12..15 read by b2 -> must be 0
    }

    // ---- query fragments (B operand of QK), 2 q-tiles per wave, from global ----
    const int lane = tid & 63, w = tid >> 6;   // wave 0..3
    const int g16 = lane >> 4, c16 = lane & 15;
    f16x4 qf[2];
    int qtile[2];
    #pragma unroll
    for (int u = 0; u < 2; ++u) {
        qtile[u] = qg * 8 + w * 2 + u;         // 0..95 (>=91 unused)
        int m = qtile[u] * 16 + c16;
        #pragma unroll
        for (int j = 0; j < 4; ++j) {
            int k = g16 * 4 + j;
            float val = 0.f;
            if (k <= 8 && m < L1V && qtile[u] < NQT) {
                int i = m / 38, jj = m - i * 38;
                val = base[c * HWV + (i + k / 3) * 40 + (jj + k % 3)] * invb * SC;
            }
            qf[u][j] = (_Float16)val;          // k=9..15 zero: ones-col can't leak into scores
        }
    }
    __syncthreads();

    f32x4 accB[2] = {{0.f,0.f,0.f,0.f},{0.f,0.f,0.f,0.f}};
    f32x4 accW[2] = {{0.f,0.f,0.f,0.f},{0.f,0.f,0.f,0.f}};
    int BT = NQT - qtr * NTIL;                 // base tiles in this quarter
    if (BT < 0) BT = 0;
    if (BT > NTIL) BT = NTIL;

    #define ATTN_TILE(ACC)                                                        \
    {                                                                             \
        const int rb = lt * 16;                                                   \
        f16x4 af = *(const f16x4*)&panL[(rb + c16) * ROWH + g16 * 4];             \
        const int r2 = rb + g16 * 4;                                              \
        f16x4 b2;                                                                 \
        b2[0] = panL[(r2 + 0) * ROWH + c16];                                      \
        b2[1] = panL[(r2 + 1) * ROWH + c16];                                      \
        b2[2] = panL[(r2 + 2) * ROWH + c16];                                      \
        b2[3] = panL[(r2 + 3) * ROWH + c16];                                      \
        _Pragma("unroll")                                                         \
        for (int u = 0; u < 2; ++u) {                                             \
            f32x4 d1 = __builtin_amdgcn_mfma_f32_16x16x16f16(af, qf[u],           \
                           (f32x4){0.f,0.f,0.f,0.f}, 0, 0, 0);                    \
            f16x4 a2;                                                             \
            a2[0] = (_Float16)__builtin_amdgcn_exp2f(d1[0]);                      \
            a2[1] = (_Float16)__builtin_amdgcn_exp2f(d1[1]);                      \
            a2[2] = (_Float16)__builtin_amdgcn_exp2f(d1[2]);                      \
            a2[3] = (_Float16)__builtin_amdgcn_exp2f(d1[3]);                      \
            ACC[u] = __builtin_amdgcn_mfma_f32_16x16x16f16(a2, b2, ACC[u],        \
                                                           0, 0, 0);              \
        }                                                                         \
    }

    for (int lt = 0;  lt < BT;   ++lt) ATTN_TILE(accB)
    for (int lt = BT; lt < NTIL; ++lt) ATTN_TILE(accW)
    #undef ATTN_TILE

    // ---- epilogue: partial num/den per (query, quarter) -> ws ----
    if (c16 < 10) {
        #pragma unroll
        for (int u = 0; u < 2; ++u) {
            if (qtile[u] >= NQT) continue;
            #pragma unroll
            for (int i = 0; i < 4; ++i) {
                int qs = qtile[u] * 16 + g16 * 4 + i;
                if (qs < L1V) {
                    float v = (c16 == 9) ? (accB[u][i] + accW[u][i])
                                         : fmaf(bmax, accB[u][i], wmax * accW[u][i]);
                    part[((size_t)(qtr * CRV + c) * 1536 + qs) * 10 + c16] = v;
                }
            }
        }
    }
}

// ---------------- K2b: merge key-quarters, divide by den ----------------
__global__ __launch_bounds__(256) void k_comb(const float* __restrict__ part,
                                              float* __restrict__ patches)
{
    int t = blockIdx.x * 256 + threadIdx.x;
    if (t >= CRV * L1V) return;
    int c = t / L1V, m = t - c * L1V;
    float tot[10];
    #pragma unroll
    for (int j = 0; j < 10; ++j) tot[j] = 0.f;
    #pragma unroll
    for (int q = 0; q < 4; ++q) {
        const float* p = part + ((size_t)(q * CRV + c) * 1536 + m) * 10;
        #pragma unroll
        for (int j = 0; j < 10; ++j) tot[j] += p[j];
    }
    float inv = 1.0f / tot[9];
    #pragma unroll
    for (int k = 0; k < 9; ++k)
        patches[(c * 9 + k) * L1V + m] = tot[k] * inv;
}

// ---------------- K3: fold (sum overlapping patches) / 9 ----------------
__global__ __launch_bounds__(256) void k_fold(const float* __restrict__ patches,
                                              float* __restrict__ folded)
{
    int t = blockIdx.x * 256 + threadIdx.x;
    if (t >= CRV * HWV) return;
    int c = t / HWV, px = t - c * HWV;
    int h = px / 40, w = px - h * 40;
    float acc = 0.f;
    #pragma unroll
    for (int di = 0; di < 3; ++di) {
        int i = h - di;
        if (i < 0 || i >= 38) continue;
        #pragma unroll
        for (int dj = 0; dj < 3; ++dj) {
            int j = w - dj;
            if (j < 0 || j >= 38) continue;
            acc += patches[(c * 9 + di * 3 + dj) * L1V + i * 38 + j];
        }
    }
    folded[t] = acc * (1.0f / 9.0f);
}

// ---------------- K4: y = prelu(w3·folded + b3) + x ----------------
__global__ __launch_bounds__(256) void k_out(const float* __restrict__ folded,
    const float* __restrict__ w3, const float* __restrict__ b3, const float* __restrict__ a3,
    const float* __restrict__ x, float* __restrict__ out)
{
    int t = blockIdx.x * 256 + threadIdx.x;
    if (t >= CHV * HWV) return;
    int oc = t / HWV, px = t - oc * HWV;
    float acc = b3[oc];
    #pragma unroll
    for (int ic = 0; ic < CRV; ++ic) acc += w3[oc * CRV + ic] * folded[ic * HWV + px];
    float a = a3[0];
    float v = acc >= 0.f ? acc : a * acc;
    out[t] = v + x[t];
}

extern "C" void kernel_launch(void* const* d_in, const int* in_sizes, int n_in,
                              void* d_out, int out_size, void* d_ws, size_t ws_size,
                              hipStream_t stream)
{
    const float* x  = (const float*)d_in[0];
    const float* w1 = (const float*)d_in[1];
    const float* b1 = (const float*)d_in[2];
    const float* a1 = (const float*)d_in[3];
    const float* w2 = (const float*)d_in[4];
    const float* b2 = (const float*)d_in[5];
    const float* a2 = (const float*)d_in[6];
    const float* w3 = (const float*)d_in[7];
    const float* b3 = (const float*)d_in[8];
    const float* a3 = (const float*)d_in[9];

    float* ws      = (float*)d_ws;
    float* sumsq   = ws;                               // 2 floats (+pad to 64)
    float* base    = ws + 64;                          // 32*1600 = 51200
    float* wfb     = base + CRV * HWV;                 // 32*400  = 12800
    float* patches = wfb + 12800;                      // 32*9*1444 = 415872
    float* folded  = patches + CRV * 9 * L1V;          // 51200
    float* part    = folded + CRV * HWV;               // 4*32*1536*10 = 1966080 (~7.9MB)

    hipMemsetAsync(sumsq, 0, 2 * sizeof(float), stream);
    k_front<<<250, 256, 0, stream>>>(x, w1, b1, a1, w2, b2, a2, base, wfb, sumsq);
    k_attn<<<dim3(12, CRV, 4), 256, 0, stream>>>(base, wfb, sumsq, part);
    k_comb<<<181, 256, 0, stream>>>(part, patches);
    k_fold<<<200, 256, 0, stream>>>(patches, folded);
    k_out<<<400, 256, 0, stream>>>(folded, w3, b3, a3, x, (float*)d_out);
}

// Round 13
// 45.825 us; speedup vs baseline: 1.0657x; 1.0657x over previous
//
#include <hip/hip_runtime.h>

#define L1V 1444
#define CRV 32
#define CHV 64
#define HWV 1600
#define KQ 448           // key slots per quarter (4*448 = 1792 >= 1780 used)
#define NTIL 28          // 16-key tiles per quarter
#define ROWH 20          // f16 per LDS row (40 B; af b64 8B-aligned, b2 gathers conflict-free)
#define NQT 91           // real query tiles (1456/16)

typedef float    f32x4 __attribute__((ext_vector_type(4)));
typedef _Float16 f16x4 __attribute__((ext_vector_type(4)));

// ---------------- K1: base = prelu(w1·x), wf = prelu(w2·avgpool(x)), global sumsq ----------------
__global__ __launch_bounds__(256) void k_front(const float* __restrict__ x,
    const float* __restrict__ w1, const float* __restrict__ b1, const float* __restrict__ a1,
    const float* __restrict__ w2, const float* __restrict__ b2, const float* __restrict__ a2,
    float* __restrict__ base, float* __restrict__ wf, float* __restrict__ sumsq)
{
    int t = blockIdx.x * 256 + threadIdx.x;
    float sq = 0.f;
    if (t < CRV * HWV) {                      // blocks 0..199: base
        int c = t / HWV, px = t - c * HWV;
        float acc = b1[c];
        #pragma unroll 8
        for (int ic = 0; ic < CHV; ++ic) acc += w1[c * CHV + ic] * x[ic * HWV + px];
        float a = a1[0];
        float v = acc >= 0.f ? acc : a * acc;
        base[t] = v;
        sq = v * v;
    } else {                                   // blocks 200..249: wf
        int u = t - CRV * HWV;                 // < 12800
        int c = u / 400, p = u - c * 400;
        int i = p / 20, j = p - i * 20;
        int px0 = (2 * i) * 40 + 2 * j;
        float acc = b2[c];
        for (int ic = 0; ic < CHV; ++ic) {
            const float* xp = x + ic * HWV + px0;
            float xd = 0.25f * (xp[0] + xp[1] + xp[40] + xp[41]);
            acc += w2[c * CHV + ic] * xd;
        }
        float a = a2[0];
        float v = acc >= 0.f ? acc : a * acc;
        wf[u] = v;
        sq = v * v;
    }
    __shared__ float red[256];
    red[threadIdx.x] = sq;
    __syncthreads();
    for (int s = 128; s > 0; s >>= 1) {
        if (threadIdx.x < s) red[threadIdx.x] += red[threadIdx.x + s];
        __syncthreads();
    }
    if (threadIdx.x == 0) atomicAdd(&sumsq[blockIdx.x < 200 ? 0 : 1], red[0]);
}

// ---------------- K2: MFMA patch attention, 4 q-tiles/wave ----------------
// grid = (6 qtile-groups, 32 ch, 4 key-quarters) = 768 blocks = 3/CU exact.
// block = 256 (4 waves); wave owns 4 q-tiles (16/block). Per 16-key tile the
// wave issues 1 ds_read_b64 (af) + 4 ds_read_u16 (b2) feeding 8 MFMAs
// (4 QK + 4 PV) — 2x the amortization of R11, and key staging per channel
// halves (6 qg-blocks instead of 12). Scalar f16 converts (R11-proven; R12's
// union-punned inline-asm pkrtz read an unwritten union member -> undef/NaN).
// Keys in LDS [448][20] f16 rows: cols 0..8 pan, 9 = ones (0 on pads ->
// free den, pads contribute 0), 10..15 = 0 (read by b2), 16..19 pad.
__global__ __launch_bounds__(256, 3) void k_attn(const float* __restrict__ base,
    const float* __restrict__ wf, const float* __restrict__ sumsq,
    float* __restrict__ part)
{
    __shared__ _Float16 panL[KQ * ROWH];      // 17,920 B
    const int qg   = blockIdx.x;              // 0..5
    const int c    = blockIdx.y;
    const int qtr  = blockIdx.z;              // key quarter 0..3
    const int tid  = threadIdx.x;
    const float bmax = sqrtf(sumsq[0]);
    const float wmax = sqrtf(sumsq[1]);
    const float invb = 1.0f / bmax, invw = 1.0f / wmax;
    const float SC = 14.4269504089f;          // SCALE * log2(e)

    // ---- stage this quarter's key slots ----
    for (int s = tid; s < KQ; s += 256) {
        int g = qtr * KQ + s;
        float v[9];
        float one = 0.f;
        if (g < L1V) {
            int i = g / 38, j = g - i * 38;
            const float* src = base + c * HWV + i * 40 + j;
            #pragma unroll
            for (int kh = 0; kh < 3; ++kh)
                #pragma unroll
                for (int kw = 0; kw < 3; ++kw) v[kh * 3 + kw] = src[kh * 40 + kw] * invb;
            one = 1.f;
        } else if (g >= 1456 && g < 1780) {
            int l2 = g - 1456;
            int i = l2 / 18, j = l2 - i * 18;
            const float* src = wf + c * 400 + i * 20 + j;
            #pragma unroll
            for (int kh = 0; kh < 3; ++kh)
                #pragma unroll
                for (int kw = 0; kw < 3; ++kw) v[kh * 3 + kw] = src[kh * 20 + kw] * invw;
            one = 1.f;
        } else {
            #pragma unroll
            for (int k = 0; k < 9; ++k) v[k] = 0.f;
        }
        f16x4 r0, r1, r2a, r3;
        r0[0] = (_Float16)v[0]; r0[1] = (_Float16)v[1]; r0[2] = (_Float16)v[2]; r0[3] = (_Float16)v[3];
        r1[0] = (_Float16)v[4]; r1[1] = (_Float16)v[5]; r1[2] = (_Float16)v[6]; r1[3] = (_Float16)v[7];
        r2a[0] = (_Float16)v[8]; r2a[1] = (_Float16)one; r2a[2] = (_Float16)0.f; r2a[3] = (_Float16)0.f;
        r3 = (f16x4)(_Float16)0.f;
        _Float16* row = &panL[s * ROWH];
        *(f16x4*)&row[0]  = r0;
        *(f16x4*)&row[4]  = r1;
        *(f16x4*)&row[8]  = r2a;
        *(f16x4*)&row[12] = r3;               // cols 12..15 read by b2 -> must be 0
    }

    // ---- query fragments (B operand of QK), 4 q-tiles per wave, from global ----
    const int lane = tid & 63, w = tid >> 6;   // wave 0..3
    const int g16 = lane >> 4, c16 = lane & 15;
    f16x4 qf[4];
    int qtile[4];
    #pragma unroll
    for (int u = 0; u < 4; ++u) {
        qtile[u] = qg * 16 + w * 4 + u;        // 0..95 (>=91 unused)
        int m = qtile[u] * 16 + c16;
        #pragma unroll
        for (int j = 0; j < 4; ++j) {
            int k = g16 * 4 + j;
            float val = 0.f;
            if (k <= 8 && m < L1V && qtile[u] < NQT) {
                int i = m / 38, jj = m - i * 38;
                val = base[c * HWV + (i + k / 3) * 40 + (jj + k % 3)] * invb * SC;
            }
            qf[u][j] = (_Float16)val;          // k=9..15 zero: ones-col can't leak into scores
        }
    }
    __syncthreads();

    f32x4 accB[4] = {{0.f,0.f,0.f,0.f},{0.f,0.f,0.f,0.f},{0.f,0.f,0.f,0.f},{0.f,0.f,0.f,0.f}};
    f32x4 accW[4] = {{0.f,0.f,0.f,0.f},{0.f,0.f,0.f,0.f},{0.f,0.f,0.f,0.f},{0.f,0.f,0.f,0.f}};
    int BT = NQT - qtr * NTIL;                 // base tiles in this quarter
    if (BT < 0) BT = 0;
    if (BT > NTIL) BT = NTIL;

    #define ATTN_TILE(ACC)                                                        \
    {                                                                             \
        const int rb = lt * 16;                                                   \
        f16x4 af = *(const f16x4*)&panL[(rb + c16) * ROWH + g16 * 4];             \
        const int r2 = rb + g16 * 4;                                              \
        f16x4 b2;                                                                 \
        b2[0] = panL[(r2 + 0) * ROWH + c16];                                      \
        b2[1] = panL[(r2 + 1) * ROWH + c16];                                      \
        b2[2] = panL[(r2 + 2) * ROWH + c16];                                      \
        b2[3] = panL[(r2 + 3) * ROWH + c16];                                      \
        _Pragma("unroll")                                                         \
        for (int u = 0; u < 4; ++u) {                                             \
            f32x4 d1 = __builtin_amdgcn_mfma_f32_16x16x16f16(af, qf[u],           \
                           (f32x4){0.f,0.f,0.f,0.f}, 0, 0, 0);                    \
            f16x4 a2;                                                             \
            a2[0] = (_Float16)__builtin_amdgcn_exp2f(d1[0]);                      \
            a2[1] = (_Float16)__builtin_amdgcn_exp2f(d1[1]);                      \
            a2[2] = (_Float16)__builtin_amdgcn_exp2f(d1[2]);                      \
            a2[3] = (_Float16)__builtin_amdgcn_exp2f(d1[3]);                      \
            ACC[u] = __builtin_amdgcn_mfma_f32_16x16x16f16(a2, b2, ACC[u],        \
                                                           0, 0, 0);              \
        }                                                                         \
    }

    for (int lt = 0;  lt < BT;   ++lt) ATTN_TILE(accB)
    for (int lt = BT; lt < NTIL; ++lt) ATTN_TILE(accW)
    #undef ATTN_TILE

    // ---- epilogue: partial num/den per (query, quarter) -> ws ----
    if (c16 < 10) {
        #pragma unroll
        for (int u = 0; u < 4; ++u) {
            if (qtile[u] >= NQT) continue;
            #pragma unroll
            for (int i = 0; i < 4; ++i) {
                int qs = qtile[u] * 16 + g16 * 4 + i;
                if (qs < L1V) {
                    float v = (c16 == 9) ? (accB[u][i] + accW[u][i])
                                         : fmaf(bmax, accB[u][i], wmax * accW[u][i]);
                    part[((size_t)(qtr * CRV + c) * 1536 + qs) * 10 + c16] = v;
                }
            }
        }
    }
}

// ---------------- K2b: merge key-quarters, divide by den ----------------
__global__ __launch_bounds__(256) void k_comb(const float* __restrict__ part,
                                              float* __restrict__ patches)
{
    int t = blockIdx.x * 256 + threadIdx.x;
    if (t >= CRV * L1V) return;
    int c = t / L1V, m = t - c * L1V;
    float tot[10];
    #pragma unroll
    for (int j = 0; j < 10; ++j) tot[j] = 0.f;
    #pragma unroll
    for (int q = 0; q < 4; ++q) {
        const float* p = part + ((size_t)(q * CRV + c) * 1536 + m) * 10;
        #pragma unroll
        for (int j = 0; j < 10; ++j) tot[j] += p[j];
    }
    float inv = 1.0f / tot[9];
    #pragma unroll
    for (int k = 0; k < 9; ++k)
        patches[(c * 9 + k) * L1V + m] = tot[k] * inv;
}

// ---------------- K3: fold (sum overlapping patches) / 9 ----------------
__global__ __launch_bounds__(256) void k_fold(const float* __restrict__ patches,
                                              float* __restrict__ folded)
{
    int t = blockIdx.x * 256 + threadIdx.x;
    if (t >= CRV * HWV) return;
    int c = t / HWV, px = t - c * HWV;
    int h = px / 40, w = px - h * 40;
    float acc = 0.f;
    #pragma unroll
    for (int di = 0; di < 3; ++di) {
        int i = h - di;
        if (i < 0 || i >= 38) continue;
        #pragma unroll
        for (int dj = 0; dj < 3; ++dj) {
            int j = w - dj;
            if (j < 0 || j >= 38) continue;
            acc += patches[(c * 9 + di * 3 + dj) * L1V + i * 38 + j];
        }
    }
    folded[t] = acc * (1.0f / 9.0f);
}

// ---------------- K4: y = prelu(w3·folded + b3) + x ----------------
__global__ __launch_bounds__(256) void k_out(const float* __restrict__ folded,
    const float* __restrict__ w3, const float* __restrict__ b3, const float* __restrict__ a3,
    const float* __restrict__ x, float* __restrict__ out)
{
    int t = blockIdx.x * 256 + threadIdx.x;
    if (t >= CHV * HWV) return;
    int oc = t / HWV, px = t - oc * HWV;
    float acc = b3[oc];
    #pragma unroll
    for (int ic = 0; ic < CRV; ++ic) acc += w3[oc * CRV + ic] * folded[ic * HWV + px];
    float a = a3[0];
    float v = acc >= 0.f ? acc : a * acc;
    out[t] = v + x[t];
}

extern "C" void kernel_launch(void* const* d_in, const int* in_sizes, int n_in,
                              void* d_out, int out_size, void* d_ws, size_t ws_size,
                              hipStream_t stream)
{
    const float* x  = (const float*)d_in[0];
    const float* w1 = (const float*)d_in[1];
    const float* b1 = (const float*)d_in[2];
    const float* a1 = (const float*)d_in[3];
    const float* w2 = (const float*)d_in[4];
    const float* b2 = (const float*)d_in[5];
    const float* a2 = (const float*)d_in[6];
    const float* w3 = (const float*)d_in[7];
    const float* b3 = (const float*)d_in[8];
    const float* a3 = (const float*)d_in[9];

    float* ws      = (float*)d_ws;
    float* sumsq   = ws;                               // 2 floats (+pad to 64)
    float* base    = ws + 64;                          // 32*1600 = 51200
    float* wfb     = base + CRV * HWV;                 // 32*400  = 12800
    float* patches = wfb + 12800;                      // 32*9*1444 = 415872
    float* folded  = patches + CRV * 9 * L1V;          // 51200
    float* part    = folded + CRV * HWV;               // 4*32*1536*10 = 1966080 (~7.9MB)

    hipMemsetAsync(sumsq, 0, 2 * sizeof(float), stream);
    k_front<<<250, 256, 0, stream>>>(x, w1, b1, a1, w2, b2, a2, base, wfb, sumsq);
    k_attn<<<dim3(6, CRV, 4), 256, 0, stream>>>(base, wfb, sumsq, part);
    k_comb<<<181, 256, 0, stream>>>(part, patches);
    k_fold<<<200, 256, 0, stream>>>(patches, folded);
    k_out<<<400, 256, 0, stream>>>(folded, w3, b3, a3, x, (float*)d_out);
}